// Round 7
// baseline (93.117 us; speedup 1.0000x reference)
//
#include <hip/hip_runtime.h>

#define D 256
#define MAXB 128

typedef float f32x4 __attribute__((ext_vector_type(4)));

// v6 structure (plain cached loads + NT stores, best anchor: 90.0 us).
// Single change: grid-stride row assignment -> balanced CONTIGUOUS per-wave
// chunks, so each wave emits one sequential write stream (32KB) and two
// sequential read streams (item/action) — DRAM page-hit friendly fronts.
__global__ __launch_bounds__(256) void hstu_preproc_fused(
    const float* __restrict__ item, const float* __restrict__ action,
    const float* __restrict__ c0v, const float* __restrict__ c1v,
    const int* __restrict__ item_len, const int* __restrict__ c0_len,
    const int* __restrict__ c1_len,
    float* __restrict__ out, int total_rows, int Bn) {
    __shared__ int s_oo[MAXB + 1];
    __shared__ int s_io[MAXB + 1];
    __shared__ int s_c0[MAXB + 1];
    __shared__ int s_c1[MAXB + 1];

    int t = threadIdx.x;
    int li = 0, l0 = 0, l1 = 0;
    if (t < Bn) {
        li = item_len[t];
        l0 = c0_len[t];
        l1 = c1_len[t];
    }
    if (t == 0) { s_oo[0] = 0; s_io[0] = 0; s_c0[0] = 0; s_c1[0] = 0; }
    if (t < Bn) {
        s_oo[t + 1] = 2 * li + l0 + l1;
        s_io[t + 1] = li;
        s_c0[t + 1] = l0;
        s_c1[t + 1] = l1;
    }
    __syncthreads();
    // Hillis-Steele inclusive scan over positions 1..Bn -> exclusive offsets [0..Bn]
    for (int off = 1; off < Bn; off <<= 1) {
        int a = 0, b = 0, c = 0, d = 0;
        int idx = t + 1;
        bool act = (t < Bn) && (idx > off);
        if (act) {
            a = s_oo[idx - off];
            b = s_io[idx - off];
            c = s_c0[idx - off];
            d = s_c1[idx - off];
        }
        __syncthreads();
        if (act) {
            s_oo[idx] += a;
            s_io[idx] += b;
            s_c0[idx] += c;
            s_c1[idx] += d;
        }
        __syncthreads();
    }

    // out_len tail (second reference output), float-encoded, block 0 only
    if (blockIdx.x == 0 && t < Bn) {
        out[(size_t)total_rows * D + t] = (float)(s_oo[t + 1] - s_oo[t]);
    }

    int wave = t >> 6;
    int lane = t & 63;
    int gwave = blockIdx.x * 4 + wave;
    int nwaves = gridDim.x * 4;

    // balanced contiguous chunk: base rows-per-wave = total/nwaves, first
    // `rem` waves take one extra row.
    int base = total_rows / nwaves;
    int rem  = total_rows - base * nwaves;
    int rbeg = gwave * base + (gwave < rem ? gwave : rem);
    int rend = rbeg + base + (gwave < rem ? 1 : 0);

    // sample index is monotone within the chunk: track it incrementally.
    // initial binary search for rbeg
    int s = 0;
    {
        int lo = 0, hi = Bn;
        while (hi - lo > 1) {
            int mid = (lo + hi) >> 1;
            if (rbeg >= s_oo[mid]) lo = mid; else hi = mid;
        }
        s = lo;
    }

    for (int r = rbeg; r < rend; r++) {
        while (r >= s_oo[s + 1]) s++;       // advance sample (monotone)
        int pos = r - s_oo[s];
        int l0c = s_c0[s + 1] - s_c0[s];
        int l1c = s_c1[s + 1] - s_c1[s];

        const float* src;
        if (pos < l0c) {
            src = c0v + (size_t)(s_c0[s] + pos) * D;
        } else if (pos < l0c + l1c) {
            src = c1v + (size_t)(s_c1[s] + pos - l0c) * D;
        } else {
            int q = pos - l0c - l1c;            // position within interleaved sequence
            int tk = s_io[s] + (q >> 1);        // source token row
            src = ((q & 1) ? action : item) + (size_t)tk * D;
        }

        // plain (cached) load; nontemporal store
        f32x4 v = reinterpret_cast<const f32x4*>(src)[lane];
        __builtin_nontemporal_store(
            v, reinterpret_cast<f32x4*>(out + (size_t)r * D) + lane);
    }
}

extern "C" void kernel_launch(void* const* d_in, const int* in_sizes, int n_in,
                              void* d_out, int out_size, void* d_ws, size_t ws_size,
                              hipStream_t stream) {
    const float* item   = (const float*)d_in[0];
    const float* action = (const float*)d_in[1];
    const float* c0v    = (const float*)d_in[2];
    const float* c1v    = (const float*)d_in[3];
    const int* item_len = (const int*)d_in[4];
    const int* c0_len   = (const int*)d_in[5];
    const int* c1_len   = (const int*)d_in[6];
    float* out = (float*)d_out;

    int Bn = in_sizes[4];                      // 128
    int total_rows = (out_size - Bn) / D;      // 262400

    // 2048 blocks x 256 threads = 8192 waves, fully resident (8 blocks/CU),
    // each wave owns a contiguous 32-33 row chunk.
    int grid = 2048;
    hstu_preproc_fused<<<grid, 256, 0, stream>>>(
        item, action, c0v, c1v, item_len, c0_len, c1_len, out, total_rows, Bn);
}

// Round 8
// 87.287 us; speedup vs baseline: 1.0668x; 1.0668x over previous
//
#include <hip/hip_runtime.h>

#define D 256
#define MAXB 128

typedef float f32x4 __attribute__((ext_vector_type(4)));

// v6 base (strided grid-stride front, plain cached loads, NT stores; 90.0us).
// Single change: cache-residency partitioning. item (134MB) + first 65% of
// action tokens are cached-loaded (fits 256MiB L3 with slack -> resident
// across graph replays); the remaining 35% of action is NT-loaded (bypasses
// L3, no pollution). Steady-state HBM FETCH should drop 134MB -> ~50-70MB.
__global__ __launch_bounds__(256) void hstu_preproc_fused(
    const float* __restrict__ item, const float* __restrict__ action,
    const float* __restrict__ c0v, const float* __restrict__ c1v,
    const int* __restrict__ item_len, const int* __restrict__ c0_len,
    const int* __restrict__ c1_len,
    float* __restrict__ out, int total_rows, int Bn, int nt_thresh) {
    __shared__ int s_oo[MAXB + 1];
    __shared__ int s_io[MAXB + 1];
    __shared__ int s_c0[MAXB + 1];
    __shared__ int s_c1[MAXB + 1];

    int t = threadIdx.x;
    int li = 0, l0 = 0, l1 = 0;
    if (t < Bn) {
        li = item_len[t];
        l0 = c0_len[t];
        l1 = c1_len[t];
    }
    if (t == 0) { s_oo[0] = 0; s_io[0] = 0; s_c0[0] = 0; s_c1[0] = 0; }
    if (t < Bn) {
        s_oo[t + 1] = 2 * li + l0 + l1;
        s_io[t + 1] = li;
        s_c0[t + 1] = l0;
        s_c1[t + 1] = l1;
    }
    __syncthreads();
    // Hillis-Steele inclusive scan over positions 1..Bn -> exclusive offsets [0..Bn]
    for (int off = 1; off < Bn; off <<= 1) {
        int a = 0, b = 0, c = 0, d = 0;
        int idx = t + 1;
        bool act = (t < Bn) && (idx > off);
        if (act) {
            a = s_oo[idx - off];
            b = s_io[idx - off];
            c = s_c0[idx - off];
            d = s_c1[idx - off];
        }
        __syncthreads();
        if (act) {
            s_oo[idx] += a;
            s_io[idx] += b;
            s_c0[idx] += c;
            s_c1[idx] += d;
        }
        __syncthreads();
    }

    // out_len tail (second reference output), float-encoded, block 0 only
    if (blockIdx.x == 0 && t < Bn) {
        out[(size_t)total_rows * D + t] = (float)(s_oo[t + 1] - s_oo[t]);
    }

    int wave = t >> 6;
    int lane = t & 63;
    int gwave = blockIdx.x * 4 + wave;
    int nwaves = gridDim.x * 4;

    for (int r = gwave; r < total_rows; r += nwaves) {
        // wave-uniform binary search: s with out_off[s] <= r < out_off[s+1]
        int lo = 0, hi = Bn;
        while (hi - lo > 1) {
            int mid = (lo + hi) >> 1;
            if (r >= s_oo[mid]) lo = mid; else hi = mid;
        }
        int s = lo;
        int pos = r - s_oo[s];
        int l0c = s_c0[s + 1] - s_c0[s];
        int l1c = s_c1[s + 1] - s_c1[s];

        const float* src;
        bool nt = false;                        // wave-uniform
        if (pos < l0c) {
            src = c0v + (size_t)(s_c0[s] + pos) * D;
        } else if (pos < l0c + l1c) {
            src = c1v + (size_t)(s_c1[s] + pos - l0c) * D;
        } else {
            int q = pos - l0c - l1c;            // position within interleaved sequence
            int tk = s_io[s] + (q >> 1);        // source token row
            if (q & 1) {
                src = action + (size_t)tk * D;
                nt = (tk >= nt_thresh);         // tail of action: stream, don't cache
            } else {
                src = item + (size_t)tk * D;
            }
        }

        f32x4 v;
        if (nt) {
            v = __builtin_nontemporal_load(
                reinterpret_cast<const f32x4*>(src) + lane);
        } else {
            v = reinterpret_cast<const f32x4*>(src)[lane];
        }
        __builtin_nontemporal_store(
            v, reinterpret_cast<f32x4*>(out + (size_t)r * D) + lane);
    }
}

extern "C" void kernel_launch(void* const* d_in, const int* in_sizes, int n_in,
                              void* d_out, int out_size, void* d_ws, size_t ws_size,
                              hipStream_t stream) {
    const float* item   = (const float*)d_in[0];
    const float* action = (const float*)d_in[1];
    const float* c0v    = (const float*)d_in[2];
    const float* c1v    = (const float*)d_in[3];
    const int* item_len = (const int*)d_in[4];
    const int* c0_len   = (const int*)d_in[5];
    const int* c1_len   = (const int*)d_in[6];
    float* out = (float*)d_out;

    int Bn = in_sizes[4];                      // 128
    int total_rows = (out_size - Bn) / D;      // 262400
    int total_tok  = in_sizes[0] / D;          // 131072 source tokens

    // cache item fully + 65% of action: ~221MB cached footprint < 256MiB L3
    int nt_thresh = (int)((long long)total_tok * 13 / 20);

    // 2048 blocks x 256 threads = 8192 waves, fully resident (8 blocks/CU),
    // ~32 rows per wave via grid-stride (dense collective front).
    int grid = 2048;
    hstu_preproc_fused<<<grid, 256, 0, stream>>>(
        item, action, c0v, c1v, item_len, c0_len, c1_len,
        out, total_rows, Bn, nt_thresh);
}